// Round 6
// baseline (19.689 us; speedup 1.0000x reference)
//
#include <hip/hip_runtime.h>
#include <math.h>

#define CLASS_P 360
#define ROW_STRIDE 4320      // C * P = 12 * 360
#define NF4 90               // float4 chunks per window (360/4)
#define RPW 2                // rows per wave
#define WPB 4                // waves per block (256 threads)

// One 64-lane wave handles RPW rows. All global loads issue before any
// arithmetic. Phase 1: three sums per row (S|pw|, Slw, S(lw*pw)) -- labels
// consumed immediately. One merged 6-chain butterfly. Phase 2:
// sum(exp(pw/S|pw|)) -- safe without max-subtraction since |scaled| <= 1 by
// construction. Row loss = lse*Slw - inv*S(lw*pw). Per-BLOCK partial via one
// LDS combine (2048 partials total). NO atomics, NO fences (rounds 2/4:
// same-address device atomics serialize ~10-40ns each across XCDs).
__global__ __launch_bounds__(256) void vp_main(
        const float* __restrict__ preds,
        const float* __restrict__ labels,
        const int*   __restrict__ cls,
        float* __restrict__ partial,
        int B) {
    const int wid  = threadIdx.x >> 6;
    const int lane = threadIdx.x & 63;
    const int r0   = (blockIdx.x * WPB + wid) * RPW;
    const bool has2 = lane < (NF4 - 64);   // lane < 26

    // ---- issue every load first ----
    float4 a0[RPW], a1[RPW], b0[RPW], b1[RPW];
    float  wgt[RPW];
    #pragma unroll
    for (int k = 0; k < RPW; ++k) {
        const int r  = r0 + k;
        const int rr = (r < B) ? r : 0;
        wgt[k] = (r < B) ? 1.0f : 0.0f;
        const size_t base = (size_t)rr * ROW_STRIDE + (size_t)cls[rr] * CLASS_P;
        const float4* __restrict__ p4 = (const float4*)(preds + base);
        const float4* __restrict__ l4 = (const float4*)(labels + base);
        a0[k] = p4[lane];
        b0[k] = l4[lane];
        a1[k] = make_float4(0.f, 0.f, 0.f, 0.f);
        b1[k] = make_float4(0.f, 0.f, 0.f, 0.f);
        if (has2) { a1[k] = p4[lane + 64]; b1[k] = l4[lane + 64]; }
    }

    // ---- phase 1: per-lane triple sums (labels die here) ----
    float sabs[RPW], sl[RPW], slp[RPW];
    #pragma unroll
    for (int k = 0; k < RPW; ++k) {
        sabs[k] = fabsf(a0[k].x) + fabsf(a0[k].y) + fabsf(a0[k].z) + fabsf(a0[k].w)
                + fabsf(a1[k].x) + fabsf(a1[k].y) + fabsf(a1[k].z) + fabsf(a1[k].w);
        sl[k]   = (b0[k].x + b0[k].y) + (b0[k].z + b0[k].w)
                + (b1[k].x + b1[k].y) + (b1[k].z + b1[k].w);
        slp[k]  = b0[k].x * a0[k].x + b0[k].y * a0[k].y + b0[k].z * a0[k].z + b0[k].w * a0[k].w
                + b1[k].x * a1[k].x + b1[k].y * a1[k].y + b1[k].z * a1[k].z + b1[k].w * a1[k].w;
    }

    // ---- merged butterfly: 3*RPW independent chains ----
    #pragma unroll
    for (int o = 32; o > 0; o >>= 1) {
        #pragma unroll
        for (int k = 0; k < RPW; ++k) {
            sabs[k] += __shfl_xor(sabs[k], o);
            sl[k]   += __shfl_xor(sl[k],   o);
            slp[k]  += __shfl_xor(slp[k],  o);
        }
    }

    // ---- phase 2: exp sums ----
    float inv[RPW], se[RPW];
    #pragma unroll
    for (int k = 0; k < RPW; ++k) {
        inv[k] = 1.0f / sabs[k];
        float e = __expf(a0[k].x * inv[k]) + __expf(a0[k].y * inv[k])
                + __expf(a0[k].z * inv[k]) + __expf(a0[k].w * inv[k]);
        if (has2)
            e += __expf(a1[k].x * inv[k]) + __expf(a1[k].y * inv[k])
               + __expf(a1[k].z * inv[k]) + __expf(a1[k].w * inv[k]);
        se[k] = e;
    }
    #pragma unroll
    for (int o = 32; o > 0; o >>= 1) {
        #pragma unroll
        for (int k = 0; k < RPW; ++k) se[k] += __shfl_xor(se[k], o);
    }

    float acc = 0.f;
    #pragma unroll
    for (int k = 0; k < RPW; ++k)
        acc += wgt[k] * (__logf(se[k]) * sl[k] - inv[k] * slp[k]);

    // ---- per-block partial ----
    __shared__ float sm[WPB];
    if (lane == 0) sm[wid] = acc;
    __syncthreads();
    if (threadIdx.x == 0)
        partial[blockIdx.x] = (sm[0] + sm[1]) + (sm[2] + sm[3]);
}

// Single-WAVE deterministic reduction: n4 float4 (n%4==0), no LDS, no sync.
__global__ __launch_bounds__(64) void vp_reduce(
        const float* __restrict__ partial, float* __restrict__ out, int n) {
    const float4* __restrict__ p4 = (const float4*)partial;
    const int n4 = n >> 2;
    const int lane = threadIdx.x;
    float acc = 0.f;
    for (int i = lane; i < n4; i += 64) {
        float4 v = p4[i];
        acc += (v.x + v.y) + (v.z + v.w);
    }
    #pragma unroll
    for (int o = 32; o > 0; o >>= 1) acc += __shfl_xor(acc, o);
    if (lane == 0) out[0] = acc;
}

extern "C" void kernel_launch(void* const* d_in, const int* in_sizes, int n_in,
                              void* d_out, int out_size, void* d_ws, size_t ws_size,
                              hipStream_t stream) {
    const float* preds  = (const float*)d_in[0];
    const float* labels = (const float*)d_in[1];
    const int*   cls    = (const int*)d_in[2];
    float* out = (float*)d_out;
    float* ws  = (float*)d_ws;

    const int B = in_sizes[2];                        // 16384 rows
    const int rows_per_block = WPB * RPW;             // 8
    const int blocks = (B + rows_per_block - 1) / rows_per_block;  // 2048

    vp_main<<<blocks, 256, 0, stream>>>(preds, labels, cls, ws, B);
    vp_reduce<<<1, 64, 0, stream>>>(ws, out, blocks);
}